// Round 11
// baseline (74.254 us; speedup 1.0000x reference)
//
#include <hip/hip_runtime.h>
#include <type_traits>

typedef float v2f __attribute__((ext_vector_type(2)));

constexpr int BLOCK = 256;          // 4 waves; wave w owns lags {2w, 2w+1}
constexpr int SPB = 128;            // samples per block (2 per lane)
constexpr int HALO_LO = 10;         // l_max(7) + m_max(3)
constexpr int HALO_HI = 3;          // +m_max for the c (leading) term
constexpr int SIG = SPB + HALO_LO + HALO_HI;   // 141

// ---------------- compile-time unroll helper ----------------
template<int I, int N, typename F>
__device__ __forceinline__ void unroll_for(F&& f) {
    if constexpr (I < N) {
        f(std::integral_constant<int, I>{});
        unroll_for<I + 1, N>(static_cast<F&&>(f));
    }
}

// Single fused kernel (no prefold dispatch, no d_ws round-trip).
// y[n] = sum_L x[n-L] * sum_s P_{L,s}(r[n-L+d(s)]),  d: 0,-1,-2,-3,+1,+2,+3
// slot 0 folds a[:,l]+b[:,l,0]+c[:,l,0] (identical radius at m=0).
// Wave w: lags {2w, 2w+1}; lane: samples {2*s2, 2*s2+1}.
// Coefficients folded per-block into LDS, read back with wave-uniform
// ds_read_b128 broadcasts (in-order lgkmcnt -> fine-grained waits).
__global__ void gmp_kernel(
    const float* __restrict__ x,
    const float* __restrict__ a_re, const float* __restrict__ a_im,
    const float* __restrict__ b_re, const float* __restrict__ b_im,
    const float* __restrict__ c_re, const float* __restrict__ c_im,
    float* __restrict__ out, int N)
{
    __shared__ __align__(16) float scoef[448 * 2];   // slot u: floats u*16..u*16+15
    __shared__ float2 sxc[SIG];
    __shared__ float sab[SIG];
    __shared__ float2 part[4][SPB];

    const int t = threadIdx.x;
    const int n0 = blockIdx.x * SPB;

    // ---- fold coefficients into LDS (2 scattered L2-hot loads/thread) ----
    for (int idx = t; idx < 448; idx += BLOCK) {
        int l = idx / 56;
        int rem = idx - l * 56;
        int s = rem >> 3;
        int k = rem & 7;
        int akl = k * 8 + l;               // a[k][l]; b/c[k][l][m] = akl*4 + m
        float re, im;
        if (s == 0) {
            re = a_re[akl] + b_re[akl * 4] + c_re[akl * 4];
            im = a_im[akl] + b_im[akl * 4] + c_im[akl * 4];
        } else if (s <= 3) {
            re = b_re[akl * 4 + s];
            im = b_im[akl * 4 + s];
        } else {
            re = c_re[akl * 4 + (s - 3)];
            im = c_im[akl * 4 + (s - 3)];
        }
        scoef[idx * 2]     = re;           // flat = (l*7+s)*16 + 2k
        scoef[idx * 2 + 1] = im;
    }

    // ---- stage signal + envelope with clipped halo ----
    const float2* x2 = (const float2*)x;
    if (t < SIG) {
        int g = n0 - HALO_LO + t;
        g = max(0, min(N - 1, g));
        float2 v = x2[g];
        sxc[t] = v;
        sab[t] = __builtin_amdgcn_sqrtf(fmaf(v.x, v.x, v.y * v.y));
    }
    __syncthreads();

    const int s2 = t & 63;                                   // sample lane
    const int wv = __builtin_amdgcn_readfirstlane(t >> 6);   // wave id 0..3
    // this wave's 14 slots = 2 lags * 7 slots * 16 floats = 224 floats
    const float4* cw = (const float4*)(scoef + wv * 224);

    // window: rv[i] = |x| at smem index rb + i, i = 0..8
    const int rb = 2 * s2 + 6 - 2 * wv;
    float rv[9];
    unroll_for<0, 9>([&](auto I) { rv[I.value] = sab[rb + I.value]; });
    float2 xv[3];                  // x at smem index rb + 3 + i
    unroll_for<0, 3>([&](auto I) { xv[I.value] = sxc[rb + 3 + I.value]; });

    float y0r = 0.f, y0i = 0.f, y1r = 0.f, y1i = 0.f;

    unroll_for<0, 2>([&](auto LL) {
        constexpr int ll = LL.value;       // local lag: L = 2*wv + ll
        v2f S0 = {0.f, 0.f}, S1 = {0.f, 0.f};
        unroll_for<0, 7>([&](auto Sc) {
            constexpr int s = Sc.value;
            constexpr int d = (s == 0) ? 0 : ((s <= 3) ? -s : (s - 3));
            constexpr int cb = (ll * 7 + s) * 4;   // float4 index of slot base
            // wave-uniform LDS broadcast: 4x ds_read_b128
            const float4 f0 = cw[cb + 0];          // k0 k1
            const float4 f1 = cw[cb + 1];          // k2 k3
            const float4 f2 = cw[cb + 2];          // k4 k5
            const float4 f3 = cw[cb + 3];          // k6 k7
            const float r0 = rv[4 - ll + d];
            const float r1 = rv[5 - ll + d];
            const v2f rr0 = {r0, r0};
            const v2f rr1 = {r1, r1};
            v2f acc0 = {f3.z, f3.w};               // k = 7
            v2f acc1 = acc0;
            const v2f c6 = {f3.x, f3.y};
            acc0 = __builtin_elementwise_fma(acc0, rr0, c6);
            acc1 = __builtin_elementwise_fma(acc1, rr1, c6);
            const v2f c5 = {f2.z, f2.w};
            acc0 = __builtin_elementwise_fma(acc0, rr0, c5);
            acc1 = __builtin_elementwise_fma(acc1, rr1, c5);
            const v2f c4 = {f2.x, f2.y};
            acc0 = __builtin_elementwise_fma(acc0, rr0, c4);
            acc1 = __builtin_elementwise_fma(acc1, rr1, c4);
            const v2f c3 = {f1.z, f1.w};
            acc0 = __builtin_elementwise_fma(acc0, rr0, c3);
            acc1 = __builtin_elementwise_fma(acc1, rr1, c3);
            const v2f c2 = {f1.x, f1.y};
            acc0 = __builtin_elementwise_fma(acc0, rr0, c2);
            acc1 = __builtin_elementwise_fma(acc1, rr1, c2);
            const v2f c1 = {f0.z, f0.w};
            acc0 = __builtin_elementwise_fma(acc0, rr0, c1);
            acc1 = __builtin_elementwise_fma(acc1, rr1, c1);
            const v2f c0 = {f0.x, f0.y};
            acc0 = __builtin_elementwise_fma(acc0, rr0, c0);
            acc1 = __builtin_elementwise_fma(acc1, rr1, c0);
            S0 += acc0;
            S1 += acc1;
        });
        {
            const float xre = xv[1 - ll].x, xim = xv[1 - ll].y;
            y0r = fmaf(xre, S0.x, fmaf(-xim, S0.y, y0r));
            y0i = fmaf(xre, S0.y, fmaf( xim, S0.x, y0i));
        }
        {
            const float xre = xv[2 - ll].x, xim = xv[2 - ll].y;
            y1r = fmaf(xre, S1.x, fmaf(-xim, S1.y, y1r));
            y1i = fmaf(xre, S1.y, fmaf( xim, S1.x, y1i));
        }
    });

    part[wv][2 * s2]     = make_float2(y0r, y0i);
    part[wv][2 * s2 + 1] = make_float2(y1r, y1i);
    __syncthreads();

    if (t < SPB) {
        float2 p0 = part[0][t];
        float2 p1 = part[1][t];
        float2 p2 = part[2][t];
        float2 p3 = part[3][t];
        float2 r;
        r.x = (p0.x + p1.x) + (p2.x + p3.x);
        r.y = (p0.y + p1.y) + (p2.y + p3.y);
        const int n = n0 + t;
        if (n < N) ((float2*)out)[n] = r;
    }
}

extern "C" void kernel_launch(void* const* d_in, const int* in_sizes, int n_in,
                              void* d_out, int out_size, void* d_ws, size_t ws_size,
                              hipStream_t stream) {
    const float* x    = (const float*)d_in[0];
    const float* a_re = (const float*)d_in[1];
    const float* a_im = (const float*)d_in[2];
    const float* b_re = (const float*)d_in[3];
    const float* b_im = (const float*)d_in[4];
    const float* c_re = (const float*)d_in[5];
    const float* c_im = (const float*)d_in[6];
    float* out = (float*)d_out;

    int N = in_sizes[0] / 2;
    int grid = (N + SPB - 1) / SPB;        // 2048 blocks
    gmp_kernel<<<grid, BLOCK, 0, stream>>>(x, a_re, a_im, b_re, b_im,
                                           c_re, c_im, out, N);
}